// Round 3
// baseline (189.151 us; speedup 1.0000x reference)
//
#include <hip/hip_runtime.h>
#include <math.h>

#define B_ 2
#define N_ 400
#define F_ 246
#define C_ 32
#define LBL_ 1440
#define NODE_IN_ 310   // F + 2C
#define RT_ 8          // row tile for k_out

// ---------------------------------------------------------------------------
// K1: P[b,n,c] = x[b,n,:] @ W_stack[0:F, c]   (x_i term)
//     Q[b,n,c] = x[b,n,:] @ W_stack[F:2F, c]  (x_j term)
// grid = B*N blocks, 256 threads = 4 waves. Wave w handles k = w, w+4, ...
// (chain length 62 instead of 246), LDS reduce across waves at the end.
// lanes 0-31 of each wave -> P column c, lanes 32-63 -> Q column c.
// ---------------------------------------------------------------------------
__global__ void k_pq(const float* __restrict__ x, const float* __restrict__ Ws,
                     float* __restrict__ P, float* __restrict__ Q) {
    int row  = blockIdx.x;             // b*N + n
    int tid  = threadIdx.x;            // 0..255
    int wave = tid >> 6, lane = tid & 63;
    __shared__ float xs[F_];
    __shared__ float part[4][64];
    const float* xrow = x + row * F_;
    if (tid < F_) xs[tid] = xrow[tid];
    __syncthreads();
    int c = lane & 31;
    const float* wbase = Ws + ((lane >> 5) ? F_ * C_ : 0) + c;
    float acc = 0.f;
    #pragma unroll 4
    for (int k = wave; k < F_; k += 4)
        acc += xs[k] * wbase[k * C_];
    part[wave][lane] = acc;
    __syncthreads();
    if (tid < 64) {
        float tot = part[0][tid] + part[1][tid] + part[2][tid] + part[3][tid];
        ((tid >> 5) ? Q : P)[row * C_ + (tid & 31)] = tot;
    }
}

// ---------------------------------------------------------------------------
// K2: aggregation. grid = 2*B*N blocks.
//   mode 0 (blk <  B*N): fixed i = n, loop j  -> AGG_I[b,i,c] (sum_j s*att_i)
//   mode 1 (blk >= B*N): fixed j = n, loop i  -> AGG_J[b,j,c] (sum_i s*att_j)
// a and both e directions are pre-staged to LDS in one parallel pass so the
// m-loop has no global latency in its control path; the only global access
// left is oth[] on the ~10% taken edges. 256 threads = 8 groups x 32 lanes
// (lane = channel c); a-mask is uniform per group -> no lane divergence.
// ---------------------------------------------------------------------------
__global__ void k_agg(const float* __restrict__ a, const float* __restrict__ e,
                      const float* __restrict__ Ws, const float* __restrict__ bs,
                      const float* __restrict__ alpha,
                      const float* __restrict__ Wai, const float* __restrict__ bai,
                      const float* __restrict__ Waj, const float* __restrict__ baj,
                      const float* __restrict__ P, const float* __restrict__ Q,
                      float* __restrict__ AGGI, float* __restrict__ AGGJ) {
    int blk  = blockIdx.x;
    int mode = (blk >= B_ * N_) ? 1 : 0;
    int row  = mode ? blk - B_ * N_ : blk;   // b*N + n
    int b = row / N_, n = row % N_;
    int tid = threadIdx.x;
    int c = tid & 31, g = tid >> 5;

    __shared__ float a_s[N_];       // mask for this row/col
    __shared__ float e_row[N_];     // e[n, m]  (contiguous)
    __shared__ float e_col[N_];     // e[m, n]  (strided but parallel loads)
    const float* abase = a + (size_t)b * N_ * N_;
    const float* ebase = e + (size_t)b * N_ * N_;
    for (int m = tid; m < N_; m += 256) {
        a_s[m]   = mode ? abase[m * N_ + n] : abase[n * N_ + m];
        e_row[m] = ebase[n * N_ + m];
        e_col[m] = ebase[m * N_ + n];
    }
    __syncthreads();

    float w3  = Ws[(2 * F_) * C_ + c];       // weight row for e_ij
    float w4  = Ws[(2 * F_ + 1) * C_ + c];   // weight row for e_ji
    float bsc = bs[c];
    float alc = alpha[c];
    float wat = mode ? Waj[c] : Wai[c];
    float bat = mode ? baj[0] : bai[0];

    // mode 0: own = P[b,i=n,:], other(m) = Q[b,m,:] (m = j)
    // mode 1: own = Q[b,j=n,:], other(m) = P[b,m,:] (m = i)
    const float* own = (mode ? Q : P) + row * C_;
    const float* oth = (mode ? P : Q) + b * N_ * C_;
    float ownc = own[c];

    float acc = 0.f;
    for (int m = g; m < N_; m += 8) {
        float aij = a_s[m];
        if (aij != 0.f) {                    // uniform across the 32-lane group
            float eij = mode ? e_col[m] : e_row[m];
            float eji = mode ? e_row[m] : e_col[m];
            float raw = ownc + oth[m * C_ + c] + eij * w3 + eji * w4 + bsc;
            float s = (raw >= 0.f ? raw : alc * raw) * aij;  // PReLU then mask
            float t = s * wat;               // butterfly dot over 32 channels
            t += __shfl_xor(t, 1, 32);
            t += __shfl_xor(t, 2, 32);
            t += __shfl_xor(t, 4, 32);
            t += __shfl_xor(t, 8, 32);
            t += __shfl_xor(t, 16, 32);
            float att = 1.f / (1.f + __expf(-(t + bat)));
            acc += s * att;
        }
    }
    __shared__ float part[8][C_];
    part[g][c] = acc;
    __syncthreads();
    if (tid < C_) {
        float tot = 0.f;
        #pragma unroll
        for (int gg = 0; gg < 8; ++gg) tot += part[gg][c];
        (mode ? AGGJ : AGGI)[row * C_ + c] = tot;
    }
}

// ---------------------------------------------------------------------------
// K3: x_new[b,n,f] = concat(x, agg_i, agg_j) @ W_node + b_node  (fp32 in ws)
// grid = B*N blocks, 256 threads (thread f computes one output, f < 246)
// ---------------------------------------------------------------------------
__global__ void k_node(const float* __restrict__ x, const float* __restrict__ AGGI,
                       const float* __restrict__ AGGJ, const float* __restrict__ Wn,
                       const float* __restrict__ bn, float* __restrict__ XNEW) {
    int row = blockIdx.x;
    int tid = threadIdx.x;
    __shared__ float cc[NODE_IN_];
    const float* xrow = x + row * F_;
    for (int k = tid; k < F_; k += 256) cc[k] = xrow[k];
    if (tid < C_) {
        cc[F_ + tid]      = AGGI[row * C_ + tid];
        cc[F_ + C_ + tid] = AGGJ[row * C_ + tid];
    }
    __syncthreads();
    if (tid < F_) {
        float acc = bn[tid];
        #pragma unroll 4
        for (int k = 0; k < NODE_IN_; ++k)
            acc += cc[k] * Wn[k * F_ + tid];
        XNEW[row * F_ + tid] = acc;
    }
}

// ---------------------------------------------------------------------------
// K4: out[b,n,l] = x_new[b,n,:] @ W_out[:,l] + b_out[l]
// grid = dim3(6, 100); 8-row tile reuses each W_out column-load 8x.
// Per-block W traffic 252 KB -> 147 MB total, L2-resident (Wo = 1.4 MB).
// ---------------------------------------------------------------------------
__global__ void k_out(const float* __restrict__ XNEW, const float* __restrict__ Wo,
                      const float* __restrict__ bo, float* __restrict__ out) {
    int ct  = blockIdx.x;            // column tile
    int rt  = blockIdx.y;            // row tile
    int tid = threadIdx.x;
    int l   = ct * 256 + tid;
    int r0  = rt * RT_;
    __shared__ float xs[RT_ * F_];   // 8 rows x 246 = 7.9 KB
    for (int idx = tid; idx < RT_ * F_; idx += 256)
        xs[idx] = XNEW[r0 * F_ + idx];      // rows are contiguous
    __syncthreads();
    if (l < LBL_) {
        float acc[RT_];
        #pragma unroll
        for (int r = 0; r < RT_; ++r) acc[r] = 0.f;
        const float* wcol = Wo + l;
        #pragma unroll 4
        for (int f = 0; f < F_; ++f) {
            float w = wcol[f * LBL_];        // coalesced across threads
            #pragma unroll
            for (int r = 0; r < RT_; ++r) acc[r] += xs[r * F_ + f] * w;
        }
        float bv = bo[l];
        #pragma unroll
        for (int r = 0; r < RT_; ++r)
            out[(size_t)(r0 + r) * LBL_ + l] = acc[r] + bv;
    }
}

// ---------------------------------------------------------------------------
extern "C" void kernel_launch(void* const* d_in, const int* in_sizes, int n_in,
                              void* d_out, int out_size, void* d_ws, size_t ws_size,
                              hipStream_t stream) {
    const float* x   = (const float*)d_in[0];
    const float* a   = (const float*)d_in[1];
    const float* e   = (const float*)d_in[2];
    const float* Ws  = (const float*)d_in[3];
    const float* bs  = (const float*)d_in[4];
    const float* al  = (const float*)d_in[5];
    const float* Wai = (const float*)d_in[6];
    const float* bai = (const float*)d_in[7];
    const float* Waj = (const float*)d_in[8];
    const float* baj = (const float*)d_in[9];
    const float* Wn  = (const float*)d_in[10];
    const float* bn  = (const float*)d_in[11];
    const float* Wo  = (const float*)d_in[12];
    const float* bo  = (const float*)d_in[13];

    float* ws   = (float*)d_ws;
    float* P    = ws;                       // B*N*C = 25600 floats
    float* Q    = P    + B_ * N_ * C_;
    float* AGGI = Q    + B_ * N_ * C_;
    float* AGGJ = AGGI + B_ * N_ * C_;
    float* XNEW = AGGJ + B_ * N_ * C_;      // B*N*F = 196800 floats

    k_pq  <<<B_ * N_,     256, 0, stream>>>(x, Ws, P, Q);
    k_agg <<<2 * B_ * N_, 256, 0, stream>>>(a, e, Ws, bs, al, Wai, bai, Waj, baj,
                                            P, Q, AGGI, AGGJ);
    k_node<<<B_ * N_,     256, 0, stream>>>(x, AGGI, AGGJ, Wn, bn, XNEW);
    k_out <<<dim3((LBL_ + 255) / 256, (B_ * N_) / RT_), 256, 0, stream>>>(
        XNEW, Wo, bo, (float*)d_out);
}

// Round 5
// 147.138 us; speedup vs baseline: 1.2855x; 1.2855x over previous
//
#include <hip/hip_runtime.h>
#include <math.h>

#define B_ 2
#define N_ 400
#define F_ 246
#define C_ 32
#define LBL_ 1440
#define NODE_IN_ 310   // F + 2C
#define RT_ 8          // row tile for k_out

// ---------------------------------------------------------------------------
// K1: P[b,n,c] = x[b,n,:] @ W_stack[0:F, c]   (x_i term)
//     Q[b,n,c] = x[b,n,:] @ W_stack[F:2F, c]  (x_j term)
// grid = B*N blocks, 256 threads = 4 waves, k-split by wave (chain 246->62).
// ---------------------------------------------------------------------------
__global__ void k_pq(const float* __restrict__ x, const float* __restrict__ Ws,
                     float* __restrict__ P, float* __restrict__ Q) {
    int row  = blockIdx.x;             // b*N + n
    int tid  = threadIdx.x;            // 0..255
    int wave = tid >> 6, lane = tid & 63;
    __shared__ float xs[F_];
    __shared__ float part[4][64];
    const float* xrow = x + row * F_;
    if (tid < F_) xs[tid] = xrow[tid];
    __syncthreads();
    int c = lane & 31;
    const float* wbase = Ws + ((lane >> 5) ? F_ * C_ : 0) + c;
    float acc = 0.f;
    #pragma unroll 8
    for (int k = wave; k < F_; k += 4)
        acc += xs[k] * wbase[k * C_];
    part[wave][lane] = acc;
    __syncthreads();
    if (tid < 64) {
        float tot = part[0][tid] + part[1][tid] + part[2][tid] + part[3][tid];
        ((tid >> 5) ? Q : P)[row * C_ + (tid & 31)] = tot;
    }
}

// ---------------------------------------------------------------------------
// K2: aggregation. grid = 2*B*N blocks, 256 threads = 8 groups x 32 lanes.
// a/e pre-staged to LDS; oth[] loaded UNCONDITIONALLY (pipelinable, unroll 4)
// so the m-loop has no data-dependent load serialization.
// ---------------------------------------------------------------------------
__global__ void k_agg(const float* __restrict__ a, const float* __restrict__ e,
                      const float* __restrict__ Ws, const float* __restrict__ bs,
                      const float* __restrict__ alpha,
                      const float* __restrict__ Wai, const float* __restrict__ bai,
                      const float* __restrict__ Waj, const float* __restrict__ baj,
                      const float* __restrict__ P, const float* __restrict__ Q,
                      float* __restrict__ AGGI, float* __restrict__ AGGJ) {
    int blk  = blockIdx.x;
    int mode = (blk >= B_ * N_) ? 1 : 0;
    int row  = mode ? blk - B_ * N_ : blk;   // b*N + n
    int b = row / N_, n = row % N_;
    int tid = threadIdx.x;
    int c = tid & 31, g = tid >> 5;

    __shared__ float a_s[N_];       // mask for this row/col
    __shared__ float e_row[N_];     // e[n, m]  (contiguous)
    __shared__ float e_col[N_];     // e[m, n]  (strided but parallel loads)
    const float* abase = a + (size_t)b * N_ * N_;
    const float* ebase = e + (size_t)b * N_ * N_;
    for (int m = tid; m < N_; m += 256) {
        a_s[m]   = mode ? abase[m * N_ + n] : abase[n * N_ + m];
        e_row[m] = ebase[n * N_ + m];
        e_col[m] = ebase[m * N_ + n];
    }
    __syncthreads();

    float w3  = Ws[(2 * F_) * C_ + c];       // weight row for e_ij
    float w4  = Ws[(2 * F_ + 1) * C_ + c];   // weight row for e_ji
    float bsc = bs[c];
    float alc = alpha[c];
    float wat = mode ? Waj[c] : Wai[c];
    float bat = mode ? baj[0] : bai[0];

    // mode 0: own = P[b,i=n,:], other(m) = Q[b,m,:] (m = j)
    // mode 1: own = Q[b,j=n,:], other(m) = P[b,m,:] (m = i)
    const float* own = (mode ? Q : P) + row * C_;
    const float* oth = (mode ? P : Q) + b * N_ * C_;
    float ownc = own[c];

    float acc = 0.f;
    #pragma unroll 4
    for (int m = g; m < N_; m += 8) {
        float othv = oth[m * C_ + c];        // unconditional -> stays in flight
        float aij  = a_s[m];
        if (aij != 0.f) {                    // uniform across the 32-lane group
            float eij = mode ? e_col[m] : e_row[m];
            float eji = mode ? e_row[m] : e_col[m];
            float raw = ownc + othv + eij * w3 + eji * w4 + bsc;
            float s = (raw >= 0.f ? raw : alc * raw) * aij;  // PReLU then mask
            float t = s * wat;               // butterfly dot over 32 channels
            t += __shfl_xor(t, 1, 32);
            t += __shfl_xor(t, 2, 32);
            t += __shfl_xor(t, 4, 32);
            t += __shfl_xor(t, 8, 32);
            t += __shfl_xor(t, 16, 32);
            float att = 1.f / (1.f + __expf(-(t + bat)));
            acc += s * att;
        }
    }
    __shared__ float part[8][C_];
    part[g][c] = acc;
    __syncthreads();
    if (tid < C_) {
        float tot = 0.f;
        #pragma unroll
        for (int gg = 0; gg < 8; ++gg) tot += part[gg][c];
        (mode ? AGGJ : AGGI)[row * C_ + c] = tot;
    }
}

// ---------------------------------------------------------------------------
// K3: x_new = concat(x, agg_i, agg_j) @ W_node + b_node
// 2 rows/block, 2-way k-split, 512 threads (8 waves). grid = B*N/2 = 400.
// Thread (kh = tid>>8, f = tid&255): rows share each Wn load (2 fmacs/load),
// chain 310 -> 155, LDS reduce across the two k-halves.
// ---------------------------------------------------------------------------
__global__ void k_node(const float* __restrict__ x, const float* __restrict__ AGGI,
                       const float* __restrict__ AGGJ, const float* __restrict__ Wn,
                       const float* __restrict__ bn, float* __restrict__ XNEW) {
    int row0 = blockIdx.x * 2;
    int tid  = threadIdx.x;            // 0..511
    int kh   = tid >> 8, f = tid & 255;
    __shared__ float cc[2][NODE_IN_];  // 2.5 KB
    __shared__ float part[2][256];     // k-half 1 partials, 2 rows
    if (f < F_) cc[kh][f] = x[(size_t)(row0 + kh) * F_ + f];   // kh doubles as row here
    if (f < C_) {
        cc[kh][F_ + f]      = AGGI[(row0 + kh) * C_ + f];
        cc[kh][F_ + C_ + f] = AGGJ[(row0 + kh) * C_ + f];
    }
    __syncthreads();
    int k0 = kh * 155, k1 = k0 + 155;  // 310 = 2*155
    float a0 = 0.f, a1 = 0.f;
    if (f < F_) {
        const float* wbase = Wn + f;
        #pragma unroll 8
        for (int k = k0; k < k1; ++k) {
            float w = wbase[k * F_];   // coalesced across f
            a0 += cc[0][k] * w;
            a1 += cc[1][k] * w;
        }
    }
    if (kh == 1) { part[0][f] = a0; part[1][f] = a1; }
    __syncthreads();
    if (kh == 0 && f < F_) {
        float bv = bn[f];
        XNEW[(size_t)row0 * F_ + f]       = a0 + part[0][f] + bv;
        XNEW[(size_t)(row0 + 1) * F_ + f] = a1 + part[1][f] + bv;
    }
}

// ---------------------------------------------------------------------------
// K4: out[b,n,l] = x_new[b,n,:] @ W_out[:,l] + b_out[l]
// grid = dim3(6, 100), 512 threads (8 waves): 8-row tile, 256 l-columns,
// 2-way f-split across block halves (chain 246 -> 123), LDS reduce.
// Wo L2 traffic stays 147 MB; waves/CU doubles to ~18.7.
// ---------------------------------------------------------------------------
__global__ void k_out(const float* __restrict__ XNEW, const float* __restrict__ Wo,
                      const float* __restrict__ bo, float* __restrict__ out) {
    int ct  = blockIdx.x;            // column tile
    int rt  = blockIdx.y;            // row tile
    int tid = threadIdx.x;           // 0..511
    int half = tid >> 8, lt = tid & 255;
    int l   = ct * 256 + lt;
    int r0  = rt * RT_;
    __shared__ float xs[RT_ * F_];   // 8 rows x 246 = 7.9 KB
    __shared__ float part[256][RT_]; // 8 KB, f-half-1 partials
    for (int idx = tid; idx < RT_ * F_; idx += 512)
        xs[idx] = XNEW[(size_t)r0 * F_ + idx];   // rows are contiguous
    __syncthreads();
    float acc[RT_];
    #pragma unroll
    for (int r = 0; r < RT_; ++r) acc[r] = 0.f;
    if (l < LBL_) {
        const float* wcol = Wo + l;
        int f0 = half * 123, f1 = f0 + 123;      // 246 = 2*123
        #pragma unroll 8
        for (int f = f0; f < f1; ++f) {
            float w = wcol[f * LBL_];            // coalesced across lt
            #pragma unroll
            for (int r = 0; r < RT_; ++r) acc[r] += xs[r * F_ + f] * w;
        }
    }
    if (half == 1) {
        #pragma unroll
        for (int r = 0; r < RT_; ++r) part[lt][r] = acc[r];
    }
    __syncthreads();
    if (half == 0 && l < LBL_) {
        float bv = bo[l];
        #pragma unroll
        for (int r = 0; r < RT_; ++r)
            out[(size_t)(r0 + r) * LBL_ + l] = acc[r] + part[lt][r] + bv;
    }
}

// ---------------------------------------------------------------------------
extern "C" void kernel_launch(void* const* d_in, const int* in_sizes, int n_in,
                              void* d_out, int out_size, void* d_ws, size_t ws_size,
                              hipStream_t stream) {
    const float* x   = (const float*)d_in[0];
    const float* a   = (const float*)d_in[1];
    const float* e   = (const float*)d_in[2];
    const float* Ws  = (const float*)d_in[3];
    const float* bs  = (const float*)d_in[4];
    const float* al  = (const float*)d_in[5];
    const float* Wai = (const float*)d_in[6];
    const float* bai = (const float*)d_in[7];
    const float* Waj = (const float*)d_in[8];
    const float* baj = (const float*)d_in[9];
    const float* Wn  = (const float*)d_in[10];
    const float* bn  = (const float*)d_in[11];
    const float* Wo  = (const float*)d_in[12];
    const float* bo  = (const float*)d_in[13];

    float* ws   = (float*)d_ws;
    float* P    = ws;                       // B*N*C = 25600 floats
    float* Q    = P    + B_ * N_ * C_;
    float* AGGI = Q    + B_ * N_ * C_;
    float* AGGJ = AGGI + B_ * N_ * C_;
    float* XNEW = AGGJ + B_ * N_ * C_;      // B*N*F = 196800 floats

    k_pq  <<<B_ * N_,     256, 0, stream>>>(x, Ws, P, Q);
    k_agg <<<2 * B_ * N_, 256, 0, stream>>>(a, e, Ws, bs, al, Wai, bai, Waj, baj,
                                            P, Q, AGGI, AGGJ);
    k_node<<<B_ * N_ / 2, 512, 0, stream>>>(x, AGGI, AGGJ, Wn, bn, XNEW);
    k_out <<<dim3((LBL_ + 255) / 256, (B_ * N_) / RT_), 512, 0, stream>>>(
        XNEW, Wo, bo, (float*)d_out);
}